// Round 4
// 5359.638 us; speedup vs baseline: 1.0138x; 1.0138x over previous
//
#include <hip/hip_runtime.h>
#include <math.h>

#define NU 512     // hidden units
#define BT 128     // batch
#define TT 1024    // timesteps
#define ID 128     // input dim
#define OC 10      // out classes
#define GGRP 32    // row groups
#define CWG 8      // WGs per group (col slices)
#define RROW 4     // rows per group   (GGRP*RROW = 128)
#define JCOL 64    // cols per WG      (CWG*JCOL = 512)
#define THREADS 512

static constexpr float F_EPS = 0.01f;
static constexpr float F_CT  = -0.6f;   // coefficient of B^T / C^T (beta=0.8)
static constexpr float F_GAM = 0.01f;

// ws layout (floats): h0 [0,65536) | h1 [65536,131072) | cnt ints [131072,+32768)
// Barrier flags: cnt[g*16 + slice] holds the EPOCH (t+1) last published by
// (g, slice). 16 ints (64B) per group; monotone, zeroed once by init_kernel.
#define WS_H1  65536
#define WS_CNT 131072

// LDS (dwords): hs[4][544] skewed fp32 h rows; xs double buffer 2 x [4][160].
// Skew: (r,k) -> r*544 + k + (k>>6)*4 ; (r,i) -> r*160 + i + (i>>4)*4
#define OFF_H  0
#define OFF_X0 2176
#define OFF_X1 2816
// Pad dynamic LDS to 96 KB: forces exactly 1 WG/CU so all 256 WGs are
// co-resident -> the inter-WG spin barrier cannot deadlock.
#define LDS_BYTES 98304

typedef float f32x4 __attribute__((ext_vector_type(4)));
typedef float f32x2 __attribute__((ext_vector_type(2)));
typedef int   i32x4 __attribute__((ext_vector_type(4)));

__global__ void init_kernel(float* ws) {
    int i = blockIdx.x * 256 + threadIdx.x;   // 65536 threads
    if (i < BT * NU) ws[i] = 0.0f;            // zero h0
    int* cnt = (int*)(ws + WS_CNT);
    if (i < GGRP * TT) cnt[i] = 0;            // zero epoch flags (region superset)
}

__global__ __launch_bounds__(THREADS, 2)
void scan_kernel(const float* __restrict__ x, const float* __restrict__ B,
                 const float* __restrict__ C, const float* __restrict__ Ew,
                 const float* __restrict__ Eb, float* ws)
{
    extern __shared__ float sm[];
    const int tid = threadIdx.x;
    const int bid = blockIdx.x;
    const int g = bid & (GGRP - 1);   // group (baseline grouping)
    const int slice = bid >> 5;       // col slice 0..7
    const int jbase = slice * JCOL;
    const int row0 = g * RROW;

    float* h0 = ws;
    float* h1 = ws + WS_H1;
    int* flg = (int*)(ws + WS_CNT) + g * 16;   // this group's 8 epoch flags

    // compute mapping: wave w -> 8 cols; lane = kc*8 + jl; kc = 8-way k split
    const int lane = tid & 63;
    const int w = tid >> 6;
    const int jl = lane & 7;
    const int kc = lane >> 3;
    const int cg = jbase + w * 8 + jl;     // this thread's global column
    const int k0 = kc * 64;                // this thread's k range [k0, k0+64)

    // ---- register-resident weights (constant across all 1024 steps) ----
    f32x2 rA[32], rW[32], rE[8];
    #pragma unroll
    for (int u2 = 0; u2 < 32; ++u2) {
        #pragma unroll
        for (int p = 0; p < 2; ++p) {
            int k = k0 + 2 * u2 + p;
            float dia = (k == cg) ? F_GAM : 0.0f;
            rA[u2][p] = B[(size_t)k * NU + cg] + F_CT * B[(size_t)cg * NU + k] - dia;
            rW[u2][p] = C[(size_t)k * NU + cg] + F_CT * C[(size_t)cg * NU + k] - dia;
        }
    }
    #pragma unroll
    for (int v2 = 0; v2 < 8; ++v2) {
        rE[v2][0] = Ew[(size_t)(kc * 16 + 2 * v2) * NU + cg];
        rE[v2][1] = Ew[(size_t)(kc * 16 + 2 * v2 + 1) * NU + cg];
    }
    const float ebv = Eb[cg];

    // staging mapping: each thread stages 16B of h and 4B of x
    const int sr = tid >> 7;               // row 0..3
    const int sk = (tid & 127) * 4;        // h dword base
    const int xi = tid & 127;              // x element
    const int hp = sr * 544 + sk + (sk >> 6) * 4;
    const int xp = sr * 160 + xi + (xi >> 4) * 4;
    const size_t xrow = (size_t)(row0 + sr) * TT * ID;

    // stage x for t=0
    sm[OFF_X0 + xp] = x[xrow + xi];
    __syncthreads();

    for (int t = 0; t < TT; ++t) {
        const float* hin = (t & 1) ? h1 : h0;
        float* hout = (t & 1) ? h0 : h1;
        const int xcur = (t & 1) ? OFF_X1 : OFF_X0;
        const int xnxt = (t & 1) ? OFF_X0 : OFF_X1;

        // 1. issue coherent h load (16B, IF$-fresh), then the x(t+1) load —
        //    fixed issue order [h, x]; both fire-and-forget. Clamp the x index
        //    on the last iter so exactly 2 loads are ALWAYS outstanding here
        //    (vmcnt(1) at step 3 then provably waits for h, the older one).
        f32x4 hvv;
        float xnv;
        {
            const float* src = hin + (size_t)(row0 + sr) * NU + sk;
            asm volatile("global_load_dwordx4 %0, %1, off sc0 sc1"
                         : "=v"(hvv) : "v"(src));
            const int tn = (t + 1 < TT) ? (t + 1) : t;
            const float* xsrc = x + xrow + (size_t)tn * ID + xi;
            asm volatile("global_load_dword %0, %1, off"
                         : "=v"(xnv) : "v"(xsrc));
        }

        // 2. z partials from xcur (staged last iter) — overlaps h-load latency
        f32x2 zac[RROW];
        #pragma unroll
        for (int r = 0; r < RROW; ++r) {
            zac[r] = (f32x2){0.f, 0.f};
            const float* xr = sm + xcur + r * 160 + kc * 20;
            #pragma unroll
            for (int q = 0; q < 4; ++q) {
                f32x4 xv = *(const f32x4*)(xr + q * 4);
                f32x2 xlo = __builtin_shufflevector(xv, xv, 0, 1);
                f32x2 xhi = __builtin_shufflevector(xv, xv, 2, 3);
                zac[r] = __builtin_elementwise_fma(xlo, rE[2 * q], zac[r]);
                zac[r] = __builtin_elementwise_fma(xhi, rE[2 * q + 1], zac[r]);
            }
        }

        // 3. wait for h ONLY (x stays in flight), publish h to LDS
        asm volatile("s_waitcnt vmcnt(1)" : "+v"(hvv) :: "memory");
        *(f32x4*)(sm + OFF_H + hp) = hvv;
        __syncthreads();

        // 4. h @ A and h @ W partials over this thread's 64 k (weights in VGPRs)
        f32x2 aA[RROW], aW[RROW];
        #pragma unroll
        for (int r = 0; r < RROW; ++r) {
            aA[r] = (f32x2){0.f, 0.f};
            aW[r] = zac[r];
            const float* hr = sm + OFF_H + r * 544 + kc * 68;
            #pragma unroll
            for (int q = 0; q < 16; ++q) {
                f32x4 hv = *(const f32x4*)(hr + q * 4);
                f32x2 hlo = __builtin_shufflevector(hv, hv, 0, 1);
                f32x2 hhi = __builtin_shufflevector(hv, hv, 2, 3);
                aA[r] = __builtin_elementwise_fma(hlo, rA[2 * q], aA[r]);
                aW[r] = __builtin_elementwise_fma(hlo, rW[2 * q], aW[r]);
                aA[r] = __builtin_elementwise_fma(hhi, rA[2 * q + 1], aA[r]);
                aW[r] = __builtin_elementwise_fma(hhi, rW[2 * q + 1], aW[r]);
            }
        }

        // 5. collapse f32x2 -> scalar, butterfly over kc (lane bits 3..5)
        float sA[RROW], sW[RROW];
        #pragma unroll
        for (int r = 0; r < RROW; ++r) {
            sA[r] = aA[r][0] + aA[r][1];
            sW[r] = aW[r][0] + aW[r][1];
        }
        #pragma unroll
        for (int m = 8; m <= 32; m <<= 1) {
            #pragma unroll
            for (int r = 0; r < RROW; ++r) {
                sA[r] += __shfl_xor(sA[r], m, 64);
                sW[r] += __shfl_xor(sW[r], m, 64);
            }
        }

        // 6. every lane has all 4 row sums; lane-group kc==r owns row r
        //    (agent-scope store — proven baseline coherence path)
        if (kc < RROW) {
            int r = kc;
            float hold = sm[OFF_H + r * 544 + cg + (cg >> 6) * 4];
            float hnew = hold + F_EPS * sA[r] + F_EPS * tanhf(sW[r] + ebv);
            __hip_atomic_store(hout + (size_t)(row0 + r) * NU + cg, hnew,
                               __ATOMIC_RELAXED, __HIP_MEMORY_SCOPE_AGENT);
        }

        // 7. consume the prefetched x (loaded at step 1, latency fully hidden)
        if (t + 1 < TT) {
            asm volatile("s_waitcnt vmcnt(0)" ::: "memory");
            sm[xnxt + xp] = xnv;
        }

        __syncthreads();   // all waves drain vmcnt -> h stores at IF$ (baseline mechanism)

        // 8. epoch-flag barrier: parallel RELEASE stores instead of serialized
        //    RMWs; spin reads all 8 flags in two dwordx4 (IF$-fresh).
        if (t < TT - 1) {
            if (tid == 0) {
                __hip_atomic_store(flg + slice, t + 1, __ATOMIC_RELEASE,
                                   __HIP_MEMORY_SCOPE_AGENT);
                const int e = t + 1;
                for (;;) {
                    i32x4 fa, fb;
                    asm volatile("global_load_dwordx4 %0, %2, off sc0 sc1\n\t"
                                 "global_load_dwordx4 %1, %3, off sc0 sc1\n\t"
                                 "s_waitcnt vmcnt(0)"
                                 : "=&v"(fa), "=&v"(fb)
                                 : "v"(flg), "v"(flg + 4) : "memory");
                    if (fa[0] >= e && fa[1] >= e && fa[2] >= e && fa[3] >= e &&
                        fb[0] >= e && fb[1] >= e && fb[2] >= e && fb[3] >= e)
                        break;
                    __builtin_amdgcn_s_sleep(1);
                }
            }
            __syncthreads();
        }
    }
}

__global__ void head_kernel(const float* __restrict__ ws, const float* __restrict__ Dw,
                            const float* __restrict__ Db, float* __restrict__ out)
{
    __shared__ float red2[32][16];
    int b = blockIdx.x;
    int tid = threadIdx.x;        // 512
    int j = tid & 15;
    int kc = tid >> 4;            // 0..31, 16 k each
    const float* h = ws + (size_t)b * NU;   // final h lives in h0 (TT even)
    float acc = 0.0f;
    if (j < OC) {
        for (int u = 0; u < 16; ++u) {
            int k = kc * 16 + u;
            acc += h[k] * Dw[(size_t)k * OC + j];
        }
    }
    red2[kc][j] = acc;
    __syncthreads();
    if (kc == 0 && j < OC) {
        float s = 0.0f;
        #pragma unroll
        for (int u = 0; u < 32; ++u) s += red2[u][j];
        out[(size_t)b * OC + j] = s + Db[j];
    }
}

extern "C" void kernel_launch(void* const* d_in, const int* in_sizes, int n_in,
                              void* d_out, int out_size, void* d_ws, size_t ws_size,
                              hipStream_t stream) {
    const float* x  = (const float*)d_in[0];
    const float* B  = (const float*)d_in[1];
    const float* C  = (const float*)d_in[2];
    const float* Ew = (const float*)d_in[3];
    const float* Eb = (const float*)d_in[4];
    const float* Dw = (const float*)d_in[5];
    const float* Db = (const float*)d_in[6];
    float* ws  = (float*)d_ws;
    float* out = (float*)d_out;

    (void)hipFuncSetAttribute((const void*)scan_kernel,
                              hipFuncAttributeMaxDynamicSharedMemorySize, LDS_BYTES);

    init_kernel<<<256, 256, 0, stream>>>(ws);
    scan_kernel<<<GGRP * CWG, THREADS, LDS_BYTES, stream>>>(x, B, C, Ew, Eb, ws);
    head_kernel<<<BT, THREADS, 0, stream>>>(ws, Dw, Db, out);
}

// Round 5
// 3701.623 us; speedup vs baseline: 1.4679x; 1.4479x over previous
//
#include <hip/hip_runtime.h>
#include <math.h>

#define NU 512     // hidden units
#define BT 128     // batch
#define TT 1024    // timesteps
#define ID 128     // input dim
#define OC 10      // out classes
#define GGRP 32    // row groups
#define CWG 8      // WGs per group (col slices)
#define RROW 4     // rows per group   (GGRP*RROW = 128)
#define JCOL 64    // cols per WG      (CWG*JCOL = 512)
#define THREADS 512

static constexpr float F_EPS = 0.01f;
static constexpr float F_CT  = -0.6f;   // coefficient of B^T / C^T (beta=0.8)
static constexpr float F_GAM = 0.01f;

// ws layout (u32): hx0 pairs [0,131072) | hx1 pairs [131072,262144)  (1 MB)
// Each h element is an 8B pair (f32 value bits, epoch). Buffer parity t&1
// holds epoch t. Readers poll epoch==t directly — the data is its own
// ready-flag, so NO inter-WG barrier exists. Double-buffer overwrite safety:
// a WG writes epoch t+2 only after its polls saw every peer's epoch-t+1
// write, which (program order) follows that peer's epoch-t reads.
#define WS_HX1 131072

// LDS (dwords): hs[4][544] skewed fp32 h rows; xs double buffer 2 x [4][160].
// Skew: (r,k) -> r*544 + k + (k>>6)*4 ; (r,i) -> r*160 + i + (i>>4)*4
#define OFF_H  0
#define OFF_X0 2176
#define OFF_X1 2816
// Pad dynamic LDS to 96 KB: forces exactly 1 WG/CU so all 256 WGs are
// co-resident -> the data-poll protocol cannot deadlock.
#define LDS_BYTES 98304

typedef float f32x4 __attribute__((ext_vector_type(4)));
typedef float f32x2 __attribute__((ext_vector_type(2)));
typedef int   i32x4 __attribute__((ext_vector_type(4)));
typedef int   i32x2 __attribute__((ext_vector_type(2)));

__global__ void init_kernel(float* ws) {
    int i = blockIdx.x * 256 + threadIdx.x;   // 65536 threads x 16B = 1 MB
    *(f32x4*)(ws + (size_t)i * 4) = (f32x4){0.f, 0.f, 0.f, 0.f};
    // zeroes both pair buffers: values 0.0 and epochs 0 (= t=0's tag)
}

__global__ __launch_bounds__(THREADS, 2)
void scan_kernel(const float* __restrict__ x, const float* __restrict__ B,
                 const float* __restrict__ C, const float* __restrict__ Ew,
                 const float* __restrict__ Eb, float* ws)
{
    extern __shared__ float sm[];
    const int tid = threadIdx.x;
    const int bid = blockIdx.x;
    const int g = bid & (GGRP - 1);   // group
    const int slice = bid >> 5;       // col slice 0..7
    const int jbase = slice * JCOL;
    const int row0 = g * RROW;

    unsigned* hx0 = (unsigned*)ws;
    unsigned* hx1 = (unsigned*)ws + WS_HX1;

    // compute mapping: wave w -> 8 cols; lane = kc*8 + jl; kc = 8-way k split
    const int lane = tid & 63;
    const int w = tid >> 6;
    const int jl = lane & 7;
    const int kc = lane >> 3;
    const int cg = jbase + w * 8 + jl;     // this thread's global column
    const int k0 = kc * 64;                // this thread's k range [k0, k0+64)

    // ---- register-resident weights (constant across all 1024 steps) ----
    f32x2 rA[32], rW[32], rE[8];
    #pragma unroll
    for (int u2 = 0; u2 < 32; ++u2) {
        #pragma unroll
        for (int p = 0; p < 2; ++p) {
            int k = k0 + 2 * u2 + p;
            float dia = (k == cg) ? F_GAM : 0.0f;
            rA[u2][p] = B[(size_t)k * NU + cg] + F_CT * B[(size_t)cg * NU + k] - dia;
            rW[u2][p] = C[(size_t)k * NU + cg] + F_CT * C[(size_t)cg * NU + k] - dia;
        }
    }
    #pragma unroll
    for (int v2 = 0; v2 < 8; ++v2) {
        rE[v2][0] = Ew[(size_t)(kc * 16 + 2 * v2) * NU + cg];
        rE[v2][1] = Ew[(size_t)(kc * 16 + 2 * v2 + 1) * NU + cg];
    }
    const float ebv = Eb[cg];

    // staging mapping: each thread polls 4 h pairs (32B) and stages 4B of x
    const int sr = tid >> 7;               // row 0..3
    const int sk = (tid & 127) * 4;        // h element base (4 consecutive cols)
    const int xi = tid & 127;              // x element
    const int hp = sr * 544 + sk + (sk >> 6) * 4;
    const int xp = sr * 160 + xi + (xi >> 4) * 4;
    const size_t xrow = (size_t)(row0 + sr) * TT * ID;
    const size_t pbase = ((size_t)(row0 + sr) * NU + sk) * 2;   // u32 offset of pair 0

    // stage x for t=0
    sm[OFF_X0 + xp] = x[xrow + xi];
    __syncthreads();

    for (int t = 0; t < TT; ++t) {
        const unsigned* hxin = (t & 1) ? hx1 : hx0;
        unsigned* hxout = (t & 1) ? hx0 : hx1;
        const int xcur = (t & 1) ? OFF_X1 : OFF_X0;
        const int xnxt = (t & 1) ? OFF_X0 : OFF_X1;

        // 1. POLL own 4 (value,epoch) pairs until epoch == t. IF$-fresh loads;
        //    the data is its own ready flag (no barrier, no separate flag RT).
        f32x4 hvv;
        {
            const unsigned* src = hxin + pbase;
            i32x4 p0, p1;
            for (;;) {
                asm volatile("global_load_dwordx4 %0, %2, off sc0 sc1\n\t"
                             "global_load_dwordx4 %1, %3, off sc0 sc1\n\t"
                             "s_waitcnt vmcnt(0)"
                             : "=&v"(p0), "=&v"(p1)
                             : "v"(src), "v"(src + 4) : "memory");
                if (p0[1] == t && p0[3] == t && p1[1] == t && p1[3] == t)
                    break;
                __builtin_amdgcn_s_sleep(1);
            }
            hvv[0] = __int_as_float(p0[0]);
            hvv[1] = __int_as_float(p0[2]);
            hvv[2] = __int_as_float(p1[0]);
            hvv[3] = __int_as_float(p1[2]);
        }

        // 2. publish h to LDS; issue x(t+1) prefetch (hidden under compute).
        //    Clamp on last iter so every wave always has exactly 1 x-load +
        //    1 h-store outstanding -> vmcnt(1) at step 7 provably waits x.
        *(f32x4*)(sm + OFF_H + hp) = hvv;
        float xnv;
        {
            const int tn = (t + 1 < TT) ? (t + 1) : t;
            const float* xsrc = x + xrow + (size_t)tn * ID + xi;
            asm volatile("global_load_dword %0, %1, off"
                         : "=v"(xnv) : "v"(xsrc));
        }
        __syncthreads();

        // 3. z partials from xcur (staged last iter)
        f32x2 zac[RROW];
        #pragma unroll
        for (int r = 0; r < RROW; ++r) {
            zac[r] = (f32x2){0.f, 0.f};
            const float* xr = sm + xcur + r * 160 + kc * 20;
            #pragma unroll
            for (int q = 0; q < 4; ++q) {
                f32x4 xv = *(const f32x4*)(xr + q * 4);
                f32x2 xlo = __builtin_shufflevector(xv, xv, 0, 1);
                f32x2 xhi = __builtin_shufflevector(xv, xv, 2, 3);
                zac[r] = __builtin_elementwise_fma(xlo, rE[2 * q], zac[r]);
                zac[r] = __builtin_elementwise_fma(xhi, rE[2 * q + 1], zac[r]);
            }
        }

        // 4. h @ A and h @ W partials over this thread's 64 k (weights in VGPRs)
        f32x2 aA[RROW], aW[RROW];
        #pragma unroll
        for (int r = 0; r < RROW; ++r) {
            aA[r] = (f32x2){0.f, 0.f};
            aW[r] = zac[r];
            const float* hr = sm + OFF_H + r * 544 + kc * 68;
            #pragma unroll
            for (int q = 0; q < 16; ++q) {
                f32x4 hv = *(const f32x4*)(hr + q * 4);
                f32x2 hlo = __builtin_shufflevector(hv, hv, 0, 1);
                f32x2 hhi = __builtin_shufflevector(hv, hv, 2, 3);
                aA[r] = __builtin_elementwise_fma(hlo, rA[2 * q], aA[r]);
                aW[r] = __builtin_elementwise_fma(hlo, rW[2 * q], aW[r]);
                aA[r] = __builtin_elementwise_fma(hhi, rA[2 * q + 1], aA[r]);
                aW[r] = __builtin_elementwise_fma(hhi, rW[2 * q + 1], aW[r]);
            }
        }

        // 5. collapse f32x2 -> scalar, butterfly over kc (lane bits 3..5)
        float sA[RROW], sW[RROW];
        #pragma unroll
        for (int r = 0; r < RROW; ++r) {
            sA[r] = aA[r][0] + aA[r][1];
            sW[r] = aW[r][0] + aW[r][1];
        }
        #pragma unroll
        for (int m = 8; m <= 32; m <<= 1) {
            #pragma unroll
            for (int r = 0; r < RROW; ++r) {
                sA[r] += __shfl_xor(sA[r], m, 64);
                sW[r] += __shfl_xor(sW[r], m, 64);
            }
        }

        // 6. lane-group kc==r owns row r: update + store (value, epoch t+1)
        //    as ONE dwordx2 (8B, single line) — self-validating publish.
        if (kc < RROW) {
            int r = kc;
            float hold = sm[OFF_H + r * 544 + cg + (cg >> 6) * 4];
            float hnew = hold + F_EPS * sA[r] + F_EPS * tanhf(sW[r] + ebv);
            i32x2 pv;
            pv[0] = __float_as_int(hnew);
            pv[1] = t + 1;
            unsigned* dst = hxout + ((size_t)(row0 + r) * NU + cg) * 2;
            asm volatile("global_store_dwordx2 %0, %1, off sc0 sc1"
                         :: "v"(dst), "v"(pv) : "memory");
        }

        // 7. consume prefetched x: vmcnt(1) waits the x load (older) but NOT
        //    the h store (newer) — per wave exactly {x, store} outstanding.
        asm volatile("s_waitcnt vmcnt(1)" : "+v"(xnv) :: "memory");
        if (t + 1 < TT)
            sm[xnxt + xp] = xnv;

        __syncthreads();   // protect LDS OFF_H / x buffers for next iteration
    }
}

__global__ void head_kernel(const float* __restrict__ ws, const float* __restrict__ Dw,
                            const float* __restrict__ Db, float* __restrict__ out)
{
    __shared__ float red2[32][16];
    int b = blockIdx.x;
    int tid = threadIdx.x;        // 512
    int j = tid & 15;
    int kc = tid >> 4;            // 0..31, 16 k each
    // final h: epoch TT lives in buffer parity TT&1 == 0 -> pairs at ws base
    const float* h = ws;          // value = pair[0] at u32 offset 2*(b*NU+k)
    float acc = 0.0f;
    if (j < OC) {
        for (int u = 0; u < 16; ++u) {
            int k = kc * 16 + u;
            acc += h[((size_t)b * NU + k) * 2] * Dw[(size_t)k * OC + j];
        }
    }
    red2[kc][j] = acc;
    __syncthreads();
    if (kc == 0 && j < OC) {
        float s = 0.0f;
        #pragma unroll
        for (int u = 0; u < 32; ++u) s += red2[u][j];
        out[(size_t)b * OC + j] = s + Db[j];
    }
}

extern "C" void kernel_launch(void* const* d_in, const int* in_sizes, int n_in,
                              void* d_out, int out_size, void* d_ws, size_t ws_size,
                              hipStream_t stream) {
    const float* x  = (const float*)d_in[0];
    const float* B  = (const float*)d_in[1];
    const float* C  = (const float*)d_in[2];
    const float* Ew = (const float*)d_in[3];
    const float* Eb = (const float*)d_in[4];
    const float* Dw = (const float*)d_in[5];
    const float* Db = (const float*)d_in[6];
    float* ws  = (float*)d_ws;
    float* out = (float*)d_out;

    (void)hipFuncSetAttribute((const void*)scan_kernel,
                              hipFuncAttributeMaxDynamicSharedMemorySize, LDS_BYTES);

    init_kernel<<<256, 256, 0, stream>>>(ws);
    scan_kernel<<<GGRP * CWG, THREADS, LDS_BYTES, stream>>>(x, B, C, Ew, Eb, ws);
    head_kernel<<<BT, THREADS, 0, stream>>>(ws, Dw, Db, out);
}